// Round 12
// baseline (992.863 us; speedup 1.0000x reference)
//
#include <hip/hip_runtime.h>
#include <math.h>

#define H_DIM 1024
#define SEG_LEN 18
#define N_SEG 32
#define QUOTA 9
#define GAP_THR 8.0e-4f

typedef _Float16 half8 __attribute__((ext_vector_type(8)));
typedef _Float16 half4 __attribute__((ext_vector_type(4)));
typedef float f32x4 __attribute__((ext_vector_type(4)));
typedef float f32x16 __attribute__((ext_vector_type(16)));

__device__ __forceinline__ void gload_lds16(const void* g, void* l) {
    __builtin_amdgcn_global_load_lds((const __attribute__((address_space(1))) uint32_t*)g,
                                     (__attribute__((address_space(3))) uint32_t*)l,
                                     16, 0, 0);
}

__device__ __forceinline__ float gelu_exact(float h) {
    return 0.5f * h * (1.0f + erff(h * 0.70710678118654752f));
}

// ---- pack W1 [512][1024] fp32 into two layouts ----
// B32 (2 MB): 32x32x16-frag order, 2 exact-split fp16 planes (recheck kernel).
// B16 (1 MB): 16x16x32-frag order, plane-0 only (screen kernel):
//   half-off = (ks*32 + nf16)*512 + lane*8 + j   (each frag = 1 KB contiguous)
__global__ void pack_w1_kernel(const float* __restrict__ W1,
                               _Float16* __restrict__ B32,
                               _Float16* __restrict__ B16) {
    const int bid = blockIdx.x, t = threadIdx.x;
    if (bid < 256) {
        int tid = bid * 256 + t;
        int q = tid & 127, n = tid >> 7;
        int kt = q >> 2, ksub = (q >> 1) & 1, hi = q & 1;
        int nb = n >> 8, nf = (n >> 5) & 7, nlo = n & 31;
        const float* src = W1 + (size_t)n * H_DIM + q * 8;
        float4 v0 = *(const float4*)src, v1 = *(const float4*)(src + 4);
        float xs[8] = {v0.x, v0.y, v0.z, v0.w, v1.x, v1.y, v1.z, v1.w};
        half8 h0, h1;
#pragma unroll
        for (int j = 0; j < 8; ++j) {
            _Float16 a = (_Float16)xs[j];
            float r = xs[j] - (float)a;
            h0[j] = a;
            h1[j] = (_Float16)(r * 2048.0f);
        }
        size_t base = (size_t)kt * 32768 + nb * 16384 + ksub * 4096 + nf * 512
                    + (size_t)(hi * 32 + nlo) * 8;
        *(half8*)(B32 + base) = h0;
        *(half8*)(B32 + base + 8192) = h1;
    } else {
        int tid = (bid - 256) * 256 + t;
        int lane = tid & 63, nf = (tid >> 6) & 31, ks = tid >> 11;
        int n = nf * 16 + (lane & 15), k0 = ks * 32 + (lane >> 4) * 8;
        const float* src = W1 + (size_t)n * H_DIM + k0;
        float4 v0 = *(const float4*)src, v1 = *(const float4*)(src + 4);
        float xs[8] = {v0.x, v0.y, v0.z, v0.w, v1.x, v1.y, v1.z, v1.w};
        half8 h0;
#pragma unroll
        for (int j = 0; j < 8; ++j) h0[j] = (_Float16)xs[j];
        *(half8*)(B16 + ((size_t)(ks * 32 + nf)) * 512 + lane * 8) = h0;
    }
}

// ---- stage-1 scorer: ZERO-BARRIER K-loop, per-wave-private A staging ----
// 64 rows x 256 cols (nb half), 4 waves of 64x64. Each wave loads the whole
// 64x32 A-slab itself (lane = row, 128 B/lane: 64 fully-consumed lines; 4x
// inter-wave redundancy served by L1), converts, writes to its OWN 4 KB LDS
// quadrant (dbuf). B direct from L2 in fragment order (proven R11). No
// inter-wave dependency -> no s_barrier, no waitcnt asm in the whole loop.
__global__ __launch_bounds__(256, 3)
void stage1_kernel(const float* __restrict__ X, const _Float16* __restrict__ B16,
                   const float* __restrict__ b1, const float* __restrict__ W2,
                   float* __restrict__ sparts, int tot) {
    __shared__ __align__(16) char smem[32768];   // 2 bufs x 4 waves x 4 KB; red overlays
    const int t = threadIdx.x, w = t >> 6, lane = t & 63;
    const int nb = blockIdx.y;
    const size_t m0 = (size_t)blockIdx.x * 64;

    char* q0 = smem + w * 4096;            // this wave's buf0 quadrant
    char* q1 = smem + 16384 + w * 4096;    // this wave's buf1 quadrant
    // A: lane covers block row = lane (full 128-B k-slab per step)
    const float* aRow = X + (m0 + lane) * H_DIM;
    // A frag-write base: frag mf=lane>>4, slot (lane&15)+16*j -> +j*256
    const int awo = (lane >> 4) * 1024 + (lane & 15) * 16;
    // B direct: frag (ks, nb*16 + w*4 + j) at bptr + ks*16384 + j*512 (halves)
    const _Float16* bptr = B16 + ((size_t)(nb * 16 + w * 4)) * 512 + lane * 8;

    f32x4 acc[4][4] = {};
    half8 bc0, bc1, bc2, bc3;

#define CVT_WRITE_Q(QN, R0, R1, joff)                                           \
    do {                                                                        \
        half8 h_;                                                               \
        h_[0] = (_Float16)R0.x; h_[1] = (_Float16)R0.y;                         \
        h_[2] = (_Float16)R0.z; h_[3] = (_Float16)R0.w;                         \
        h_[4] = (_Float16)R1.x; h_[5] = (_Float16)R1.y;                         \
        h_[6] = (_Float16)R1.z; h_[7] = (_Float16)R1.w;                         \
        *(half8*)((QN) + awo + (joff)) = h_;                                    \
    } while (0)

#define STEP(ks, QC, QN)                                                        \
    do {                                                                        \
        float4 r0, r1, r2, r3, r4, r5, r6, r7;                                  \
        half8 bn0, bn1, bn2, bn3;                                               \
        const bool pf = (ks) < 31;                                              \
        if (pf) {                                                               \
            const _Float16* bp = bptr + (size_t)((ks) + 1) * 16384;             \
            bn0 = *(const half8*)(bp);                                          \
            bn1 = *(const half8*)(bp + 512);                                    \
            bn2 = *(const half8*)(bp + 1024);                                   \
            bn3 = *(const half8*)(bp + 1536);                                   \
            const float* ap = aRow + ((ks) + 1) * 32;                           \
            r0 = *(const float4*)(ap);      r1 = *(const float4*)(ap + 4);      \
            r2 = *(const float4*)(ap + 8);  r3 = *(const float4*)(ap + 12);     \
            r4 = *(const float4*)(ap + 16); r5 = *(const float4*)(ap + 20);     \
            r6 = *(const float4*)(ap + 24); r7 = *(const float4*)(ap + 28);     \
        }                                                                       \
        half8 a0 = *(const half8*)((QC) + 0 * 1024 + lane * 16);                \
        half8 a1 = *(const half8*)((QC) + 1 * 1024 + lane * 16);                \
        half8 a2 = *(const half8*)((QC) + 2 * 1024 + lane * 16);                \
        half8 a3 = *(const half8*)((QC) + 3 * 1024 + lane * 16);                \
        __builtin_amdgcn_s_setprio(1);                                          \
        acc[0][0] = __builtin_amdgcn_mfma_f32_16x16x32_f16(a0, bc0, acc[0][0], 0, 0, 0); \
        acc[0][1] = __builtin_amdgcn_mfma_f32_16x16x32_f16(a0, bc1, acc[0][1], 0, 0, 0); \
        acc[0][2] = __builtin_amdgcn_mfma_f32_16x16x32_f16(a0, bc2, acc[0][2], 0, 0, 0); \
        acc[0][3] = __builtin_amdgcn_mfma_f32_16x16x32_f16(a0, bc3, acc[0][3], 0, 0, 0); \
        acc[1][0] = __builtin_amdgcn_mfma_f32_16x16x32_f16(a1, bc0, acc[1][0], 0, 0, 0); \
        acc[1][1] = __builtin_amdgcn_mfma_f32_16x16x32_f16(a1, bc1, acc[1][1], 0, 0, 0); \
        acc[1][2] = __builtin_amdgcn_mfma_f32_16x16x32_f16(a1, bc2, acc[1][2], 0, 0, 0); \
        acc[1][3] = __builtin_amdgcn_mfma_f32_16x16x32_f16(a1, bc3, acc[1][3], 0, 0, 0); \
        acc[2][0] = __builtin_amdgcn_mfma_f32_16x16x32_f16(a2, bc0, acc[2][0], 0, 0, 0); \
        acc[2][1] = __builtin_amdgcn_mfma_f32_16x16x32_f16(a2, bc1, acc[2][1], 0, 0, 0); \
        acc[2][2] = __builtin_amdgcn_mfma_f32_16x16x32_f16(a2, bc2, acc[2][2], 0, 0, 0); \
        acc[2][3] = __builtin_amdgcn_mfma_f32_16x16x32_f16(a2, bc3, acc[2][3], 0, 0, 0); \
        acc[3][0] = __builtin_amdgcn_mfma_f32_16x16x32_f16(a3, bc0, acc[3][0], 0, 0, 0); \
        acc[3][1] = __builtin_amdgcn_mfma_f32_16x16x32_f16(a3, bc1, acc[3][1], 0, 0, 0); \
        acc[3][2] = __builtin_amdgcn_mfma_f32_16x16x32_f16(a3, bc2, acc[3][2], 0, 0, 0); \
        acc[3][3] = __builtin_amdgcn_mfma_f32_16x16x32_f16(a3, bc3, acc[3][3], 0, 0, 0); \
        __builtin_amdgcn_s_setprio(0);                                          \
        if (pf) {                                                               \
            CVT_WRITE_Q(QN, r0, r1, 0);                                         \
            CVT_WRITE_Q(QN, r2, r3, 256);                                       \
            CVT_WRITE_Q(QN, r4, r5, 512);                                       \
            CVT_WRITE_Q(QN, r6, r7, 768);                                       \
            bc0 = bn0; bc1 = bn1; bc2 = bn2; bc3 = bn3;                         \
        }                                                                       \
    } while (0)

    // ---- prologue: fill own buf0 with A(0); load B(0) ----
    {
        float4 r0 = *(const float4*)(aRow);      float4 r1 = *(const float4*)(aRow + 4);
        float4 r2 = *(const float4*)(aRow + 8);  float4 r3 = *(const float4*)(aRow + 12);
        float4 r4 = *(const float4*)(aRow + 16); float4 r5 = *(const float4*)(aRow + 20);
        float4 r6 = *(const float4*)(aRow + 24); float4 r7 = *(const float4*)(aRow + 28);
        bc0 = *(const half8*)(bptr);
        bc1 = *(const half8*)(bptr + 512);
        bc2 = *(const half8*)(bptr + 1024);
        bc3 = *(const half8*)(bptr + 1536);
        CVT_WRITE_Q(q0, r0, r1, 0);
        CVT_WRITE_Q(q0, r2, r3, 256);
        CVT_WRITE_Q(q0, r4, r5, 512);
        CVT_WRITE_Q(q0, r6, r7, 768);
    }

    for (int ks2 = 0; ks2 < 16; ++ks2) {
        STEP(2 * ks2,     q0, q1);
        STEP(2 * ks2 + 1, q1, q0);
    }

    // epilogue: h = acc + b1; gelu; *W2; reduce 256 cols -> partial scores
    __syncthreads();   // only barrier in the kernel: red overlays all quadrants
    float* red = (float*)smem;  // [4][64][17]
    const int hi = lane >> 4, lc = lane & 15;
    float b1v[4], w2v[4];
#pragma unroll
    for (int nf = 0; nf < 4; ++nf) {
        int c = nb * 256 + w * 64 + nf * 16 + lc;
        b1v[nf] = b1[c];
        w2v[nf] = W2[c];
    }
#pragma unroll
    for (int mf = 0; mf < 4; ++mf) {
#pragma unroll
        for (int i = 0; i < 4; ++i) {
            float s = 0.f;
#pragma unroll
            for (int nf = 0; nf < 4; ++nf) {
                float h = acc[mf][nf][i] + b1v[nf];
                s = fmaf(gelu_exact(h), w2v[nf], s);
            }
            red[(w * 64 + mf * 16 + hi * 4 + i) * 17 + lc] = s;
        }
    }
    __syncthreads();
    if (t < 64) {
        float s = 0.f;
#pragma unroll
        for (int ww = 0; ww < 4; ++ww)
#pragma unroll
            for (int c = 0; c < 16; ++c) s += red[(ww * 64 + t) * 17 + c];
        sparts[(size_t)nb * tot + m0 + t] = s;
    }
}

// ---- flag + provisional select from screen scores ----
__global__ void flag_select_kernel(const float* __restrict__ sparts, int tot,
                                   int* __restrict__ sel_buf,
                                   int* __restrict__ flag_list,
                                   int* __restrict__ counter, int N, int nseg_tot) {
    int seg = blockIdx.x * 256 + threadIdx.x;
    if (seg >= nseg_tot) return;
    int b = seg >> 5, s = seg & 31;
    size_t base = (size_t)b * N + s * SEG_LEN;
    float sc[SEG_LEN];
#pragma unroll
    for (int j = 0; j < SEG_LEN; ++j) sc[j] = sparts[base + j] + sparts[base + j + tot];
    unsigned mask = 0;
    float best9 = 0.f;
    for (int it = 0; it < QUOTA; ++it) {
        float best = 0.f; int bi = 0; bool found = false;
        for (int i = 0; i < SEG_LEN; ++i) if (!((mask >> i) & 1u)) {
            if (!found || sc[i] > best) { best = sc[i]; bi = i; found = true; }
        }
        mask |= 1u << bi;
        best9 = best;
    }
    float best10 = 0.f; bool f10 = false;
    for (int i = 0; i < SEG_LEN; ++i) if (!((mask >> i) & 1u)) {
        if (!f10 || sc[i] > best10) { best10 = sc[i]; f10 = true; }
    }
    if (best9 - best10 > GAP_THR) {
        int c = 0;
        for (int i = 0; i < SEG_LEN; ++i)
            if ((mask >> i) & 1u) sel_buf[(size_t)seg * QUOTA + (c++)] = i;
    } else {
        int p = atomicAdd(counter, 1);
        flag_list[p] = seg;
    }
}

// ---- exact recheck (fp16-split 3-pass, proven numerics) of flagged segments ----
__global__ __launch_bounds__(512, 2)
void recheck_kernel(const float* __restrict__ X, const _Float16* __restrict__ B32,
                    const float* __restrict__ b1, const float* __restrict__ W2,
                    const int* __restrict__ flag_list, const int* __restrict__ counter,
                    int* __restrict__ sel_buf, int N) {
    const int count = *counter;
    const int jb = blockIdx.x;
    if (jb * 3 >= count) return;
    __shared__ __align__(16) char smem[73728];
    const int t = threadIdx.x, w = t >> 6, lane = t & 63;

    const int r_ = t >> 3, kq8 = t & 7;
    int q = r_ / 18, rr = r_ % 18;
    if (r_ >= 54) { q = 2; rr = 0; }
    int li = jb * 3 + q; if (li >= count) li = count - 1;
    const int sg = flag_list[li];
    const float* aRow = X + ((size_t)(sg >> 5) * N + (sg & 31) * SEG_LEN + rr) * H_DIM + kq8 * 4;
    const int rg = r_ >> 5, aks = kq8 >> 2, ahi = (kq8 >> 1) & 1;
    const int aoff = (rg * 2 + aks) * 1024 + (ahi * 32 + (r_ & 31)) * 16 + (kq8 & 1) * 8;

    f32x16 acc1[2][2] = {};
    f32x16 acc2[2][2] = {};
    float4 av = *(const float4*)aRow;

    for (int kt = 0; kt < 32; ++kt) {
#pragma unroll
        for (int r8 = 0; r8 < 8; ++r8) {
            int idx = r8 * 512 + t;
            gload_lds16(B32 + (size_t)kt * 32768 + (size_t)idx * 8,
                        smem + 8192 + (size_t)idx * 16);
        }
        {
            float xs[4] = {av.x, av.y, av.z, av.w};
            half4 h0, h1;
#pragma unroll
            for (int j = 0; j < 4; ++j) {
                _Float16 a = (_Float16)xs[j];
                float r = xs[j] - (float)a;
                h0[j] = a;
                h1[j] = (_Float16)(r * 2048.0f);
            }
            *(half4*)(smem + aoff) = h0;
            *(half4*)(smem + 4096 + aoff) = h1;
        }
        int ktn = kt < 31 ? kt + 1 : 31;
        av = *(const float4*)(aRow + ktn * 32);
        asm volatile("s_waitcnt vmcnt(1) lgkmcnt(0)" ::: "memory");
        __builtin_amdgcn_sched_barrier(0);
        __builtin_amdgcn_s_barrier();

        half8 a0[4], a1[4], b0[4], b1f[4];
#pragma unroll
        for (int mf = 0; mf < 2; ++mf)
#pragma unroll
            for (int ks2 = 0; ks2 < 2; ++ks2) {
                a0[mf * 2 + ks2] = *(const half8*)(smem + (mf * 2 + ks2) * 1024 + lane * 16);
                a1[mf * 2 + ks2] = *(const half8*)(smem + 4096 + (mf * 2 + ks2) * 1024 + lane * 16);
            }
        const char* bb = smem + 8192 + (w >> 2) * 32768;
#pragma unroll
        for (int nfl = 0; nfl < 2; ++nfl)
#pragma unroll
            for (int ks2 = 0; ks2 < 2; ++ks2) {
                b0[nfl * 2 + ks2]  = *(const half8*)(bb + ks2 * 8192 + ((w & 3) * 2 + nfl) * 1024 + lane * 16);
                b1f[nfl * 2 + ks2] = *(const half8*)(bb + 16384 + ks2 * 8192 + ((w & 3) * 2 + nfl) * 1024 + lane * 16);
            }
        __builtin_amdgcn_s_setprio(1);
#pragma unroll
        for (int mf = 0; mf < 2; ++mf)
#pragma unroll
            for (int nfl = 0; nfl < 2; ++nfl)
#pragma unroll
                for (int ks2 = 0; ks2 < 2; ++ks2)
                    acc1[mf][nfl] = __builtin_amdgcn_mfma_f32_32x32x16_f16(
                        a0[mf * 2 + ks2], b0[nfl * 2 + ks2], acc1[mf][nfl], 0, 0, 0);
#pragma unroll
        for (int mf = 0; mf < 2; ++mf)
#pragma unroll
            for (int nfl = 0; nfl < 2; ++nfl)
#pragma unroll
                for (int ks2 = 0; ks2 < 2; ++ks2)
                    acc2[mf][nfl] = __builtin_amdgcn_mfma_f32_32x32x16_f16(
                        a0[mf * 2 + ks2], b1f[nfl * 2 + ks2], acc2[mf][nfl], 0, 0, 0);
#pragma unroll
        for (int mf = 0; mf < 2; ++mf)
#pragma unroll
            for (int nfl = 0; nfl < 2; ++nfl)
#pragma unroll
                for (int ks2 = 0; ks2 < 2; ++ks2)
                    acc2[mf][nfl] = __builtin_amdgcn_mfma_f32_32x32x16_f16(
                        a1[mf * 2 + ks2], b0[nfl * 2 + ks2], acc2[mf][nfl], 0, 0, 0);
        __builtin_amdgcn_s_setprio(0);
        __builtin_amdgcn_s_barrier();
    }

    __syncthreads();
    float* red = (float*)smem;                 // [8][64][33]
    float b1v[2], w2v[2];
#pragma unroll
    for (int nfl = 0; nfl < 2; ++nfl) {
        int c = (w >> 2) * 256 + ((w & 3) * 2 + nfl) * 32 + (lane & 31);
        b1v[nfl] = b1[c];
        w2v[nfl] = W2[c];
    }
#pragma unroll
    for (int mf = 0; mf < 2; ++mf)
#pragma unroll
        for (int i = 0; i < 16; ++i) {
            float s = 0.f;
#pragma unroll
            for (int nfl = 0; nfl < 2; ++nfl) {
                float h = acc1[mf][nfl][i] + acc2[mf][nfl][i] * (1.0f / 2048.0f) + b1v[nfl];
                s = fmaf(gelu_exact(h), w2v[nfl], s);
            }
            int row = mf * 32 + (i & 3) + 8 * (i >> 2) + 4 * (lane >> 5);
            red[(w * 64 + row) * 33 + (lane & 31)] = s;
        }
    __syncthreads();
    float* sx = (float*)(smem + 67584);        // [64]
    if (t < 64) {
        float s = 0.f;
        for (int ww = 0; ww < 8; ++ww)
#pragma unroll
            for (int lc = 0; lc < 32; ++lc) s += red[(ww * 64 + t) * 33 + lc];
        sx[t] = s;
    }
    __syncthreads();
    if (t < 3 && jb * 3 + t < count) {
        int sg2 = flag_list[jb * 3 + t];
        const float* sv = sx + t * SEG_LEN;
        unsigned mask = 0;
        for (int it = 0; it < QUOTA; ++it) {
            float best = 0.f; int bi = 0; bool found = false;
            for (int i = 0; i < SEG_LEN; ++i) if (!((mask >> i) & 1u)) {
                if (!found || sv[i] > best) { best = sv[i]; bi = i; found = true; }
            }
            mask |= 1u << bi;
        }
        int c = 0;
        for (int i = 0; i < SEG_LEN; ++i)
            if ((mask >> i) & 1u) sel_buf[(size_t)sg2 * QUOTA + (c++)] = i;
    }
}

// ---- final gather of selected rows ----
__global__ void gather_kernel(const float* __restrict__ X, const int* __restrict__ sel_buf,
                              float* __restrict__ out, int N) {
    const int seg = blockIdx.x, b = blockIdx.y, t = threadIdx.x;
    const int* sel = sel_buf + ((size_t)b * N_SEG + seg) * QUOTA;
    const float4* xb = (const float4*)X + ((size_t)b * N + seg * SEG_LEN) * (H_DIM / 4);
    float4* ob = (float4*)out + ((size_t)b * N_SEG * QUOTA + seg * QUOTA) * (H_DIM / 4);
#pragma unroll
    for (int j = 0; j < QUOTA; ++j) {
        int r = sel[j];
        ob[(size_t)j * (H_DIM / 4) + t] = xb[(size_t)r * (H_DIM / 4) + t];
    }
}

extern "C" void kernel_launch(void* const* d_in, const int* in_sizes, int n_in,
                              void* d_out, int out_size, void* d_ws, size_t ws_size,
                              hipStream_t stream) {
    const float* X  = (const float*)d_in[0];
    const float* W1 = (const float*)d_in[1];
    const float* b1 = (const float*)d_in[2];
    const float* W2 = (const float*)d_in[3];
    float* out = (float*)d_out;

    const int Hh = in_sizes[2];                        // 512
    const int H  = Hh * 2;                             // 1024
    const long long TOT = (long long)in_sizes[0] / H;  // 147456 tokens
    const int B = 256;
    const int N = (int)(TOT / B);                      // 576
    const int nseg_tot = B * N_SEG;                    // 8192

    char* ws = (char*)d_ws;
    _Float16* B32 = (_Float16*)(ws + 0);               // 2 MB
    _Float16* B16 = (_Float16*)(ws + 2097152);         // 1 MB
    float* sparts = (float*)(ws + 3145728);            // 2*TOT f32
    int* sel_buf  = (int*)(ws + 4325376);              // 8192*9
    int* flag_list= (int*)(ws + 4620288);              // 8192
    int* counter  = (int*)(ws + 4653056);

    hipMemsetAsync(counter, 0, 16, stream);

    hipLaunchKernelGGL(pack_w1_kernel, dim3(512), dim3(256), 0, stream, W1, B32, B16);

    hipLaunchKernelGGL(stage1_kernel, dim3((unsigned)(TOT / 64), 2), dim3(256), 0, stream,
                       X, B16, b1, W2, sparts, (int)TOT);

    hipLaunchKernelGGL(flag_select_kernel, dim3((nseg_tot + 255) / 256), dim3(256), 0, stream,
                       sparts, (int)TOT, sel_buf, flag_list, counter, N, nseg_tot);

    hipLaunchKernelGGL(recheck_kernel, dim3((nseg_tot + 2) / 3), dim3(512), 0, stream,
                       X, B32, b1, W2, flag_list, counter, sel_buf, N);

    hipLaunchKernelGGL(gather_kernel, dim3(N_SEG, B), dim3(256), 0, stream,
                       X, sel_buf, out, N);
}

// Round 13
// 613.517 us; speedup vs baseline: 1.6183x; 1.6183x over previous
//
#include <hip/hip_runtime.h>
#include <math.h>

#define H_DIM 1024
#define SEG_LEN 18
#define N_SEG 32
#define QUOTA 9
#define GAP_THR 8.0e-4f

typedef _Float16 half8 __attribute__((ext_vector_type(8)));
typedef _Float16 half4 __attribute__((ext_vector_type(4)));
typedef float f32x4 __attribute__((ext_vector_type(4)));
typedef float f32x16 __attribute__((ext_vector_type(16)));

__device__ __forceinline__ void gload_lds16(const void* g, void* l) {
    __builtin_amdgcn_global_load_lds((const __attribute__((address_space(1))) uint32_t*)g,
                                     (__attribute__((address_space(3))) uint32_t*)l,
                                     16, 0, 0);
}

__device__ __forceinline__ float gelu_exact(float h) {
    return 0.5f * h * (1.0f + erff(h * 0.70710678118654752f));
}

// ---- pack W1 [512][1024] fp32 into two layouts ----
// B32 (2 MB): 32x32x16-frag order, 2 exact-split fp16 planes (recheck kernel).
// B16 (1 MB): 16x16x32-frag order, plane-0 only (screen kernel):
//   half-off = (ks*32 + nf16)*512 + lane*8 + j   (each frag = 1 KB contiguous)
__global__ void pack_w1_kernel(const float* __restrict__ W1,
                               _Float16* __restrict__ B32,
                               _Float16* __restrict__ B16) {
    const int bid = blockIdx.x, t = threadIdx.x;
    if (bid < 256) {
        int tid = bid * 256 + t;
        int q = tid & 127, n = tid >> 7;
        int kt = q >> 2, ksub = (q >> 1) & 1, hi = q & 1;
        int nb = n >> 8, nf = (n >> 5) & 7, nlo = n & 31;
        const float* src = W1 + (size_t)n * H_DIM + q * 8;
        float4 v0 = *(const float4*)src, v1 = *(const float4*)(src + 4);
        float xs[8] = {v0.x, v0.y, v0.z, v0.w, v1.x, v1.y, v1.z, v1.w};
        half8 h0, h1;
#pragma unroll
        for (int j = 0; j < 8; ++j) {
            _Float16 a = (_Float16)xs[j];
            float r = xs[j] - (float)a;
            h0[j] = a;
            h1[j] = (_Float16)(r * 2048.0f);
        }
        size_t base = (size_t)kt * 32768 + nb * 16384 + ksub * 4096 + nf * 512
                    + (size_t)(hi * 32 + nlo) * 8;
        *(half8*)(B32 + base) = h0;
        *(half8*)(B32 + base + 8192) = h1;
    } else {
        int tid = (bid - 256) * 256 + t;
        int lane = tid & 63, nf = (tid >> 6) & 31, ks = tid >> 11;
        int n = nf * 16 + (lane & 15), k0 = ks * 32 + (lane >> 4) * 8;
        const float* src = W1 + (size_t)n * H_DIM + k0;
        float4 v0 = *(const float4*)src, v1 = *(const float4*)(src + 4);
        float xs[8] = {v0.x, v0.y, v0.z, v0.w, v1.x, v1.y, v1.z, v1.w};
        half8 h0;
#pragma unroll
        for (int j = 0; j < 8; ++j) h0[j] = (_Float16)xs[j];
        *(half8*)(B16 + ((size_t)(ks * 32 + nf)) * 512 + lane * 8) = h0;
    }
}

// ---- stage-1 scorer: 128x64 wave tiles (32 MFMA/step), B direct from L2 ----
// Block = 128 rows x 256 cols (nb half); 4 waves side-by-side in N, each
// covering ALL 128 rows x 64 cols. A-frags (8 KB/step) staged cooperatively
// in LDS dbuf, shared by all 4 waves; B read straight from L2 in fragment
// order. One lgkm-only barrier per K-step.
__global__ __launch_bounds__(256, 2)
void stage1_kernel(const float* __restrict__ X, const _Float16* __restrict__ B16,
                   const float* __restrict__ b1, const float* __restrict__ W2,
                   float* __restrict__ sparts, int tot) {
    __shared__ __align__(16) char smem[36864];  // A dbuf 2x8KB; red[128][68] overlays
    const int t = threadIdx.x, w = t >> 6, lane = t & 63;
    const int nb = blockIdx.y;
    const size_t m0 = (size_t)blockIdx.x * 128;

    // A staging: thread t -> row t>>1 (0..127), half (t&1) => elements 16h..16h+15
    const int arow = t >> 1;
    const int ahalf = t & 1;
    const float* aptr = X + (m0 + arow) * H_DIM + ahalf * 16;
    // write offsets: frag mf = arow>>4; octets o = 2h, 2h+1
    const int awo0 = (arow >> 4) * 1024 + ((arow & 15) + 16 * (ahalf * 2)) * 16;
    const int awo1 = (arow >> 4) * 1024 + ((arow & 15) + 16 * (ahalf * 2 + 1)) * 16;
    // B direct: frag (ks, nb*16 + w*4 + j) at bptr + ks*16384 + j*512 halves
    const _Float16* bptr = B16 + ((size_t)(nb * 16 + w * 4)) * 512 + lane * 8;

    f32x4 acc[8][4] = {};
    float4 ar0, ar1, ar2, ar3;           // raw A for next cvt (16 elements)
    half8 bc0, bc1, bc2, bc3;

#define A_LOAD(kt)                                                              \
    do {                                                                        \
        const float* p_ = aptr + (kt) * 32;                                     \
        ar0 = *(const float4*)(p_);                                             \
        ar1 = *(const float4*)(p_ + 4);                                         \
        ar2 = *(const float4*)(p_ + 8);                                         \
        ar3 = *(const float4*)(p_ + 12);                                        \
    } while (0)

#define A_CVT_WRITE(buf)                                                        \
    do {                                                                        \
        half8 h0_, h1_;                                                         \
        h0_[0] = (_Float16)ar0.x; h0_[1] = (_Float16)ar0.y;                     \
        h0_[2] = (_Float16)ar0.z; h0_[3] = (_Float16)ar0.w;                     \
        h0_[4] = (_Float16)ar1.x; h0_[5] = (_Float16)ar1.y;                     \
        h0_[6] = (_Float16)ar1.z; h0_[7] = (_Float16)ar1.w;                     \
        h1_[0] = (_Float16)ar2.x; h1_[1] = (_Float16)ar2.y;                     \
        h1_[2] = (_Float16)ar2.z; h1_[3] = (_Float16)ar2.w;                     \
        h1_[4] = (_Float16)ar3.x; h1_[5] = (_Float16)ar3.y;                     \
        h1_[6] = (_Float16)ar3.z; h1_[7] = (_Float16)ar3.w;                     \
        *(half8*)(smem + (buf) * 8192 + awo0) = h0_;                            \
        *(half8*)(smem + (buf) * 8192 + awo1) = h1_;                            \
    } while (0)

#define STEP(ks, CB, NBUF)                                                      \
    do {                                                                        \
        half8 bn0, bn1, bn2, bn3;                                               \
        const bool pf1 = (ks) < 31;                                             \
        if (pf1) {                                                              \
            const _Float16* bp = bptr + (size_t)((ks) + 1) * 16384;             \
            bn0 = *(const half8*)(bp);                                          \
            bn1 = *(const half8*)(bp + 512);                                    \
            bn2 = *(const half8*)(bp + 1024);                                   \
            bn3 = *(const half8*)(bp + 1536);                                   \
            A_CVT_WRITE(NBUF);               /* consumes araw = A(ks+1) */      \
            if ((ks) < 30) A_LOAD((ks) + 2); /* refill araw, 1.5-step cover */  \
        }                                                                       \
        half8 a0 = *(const half8*)(smem + (CB) * 8192 + 0 * 1024 + lane * 16);  \
        half8 a1 = *(const half8*)(smem + (CB) * 8192 + 1 * 1024 + lane * 16);  \
        half8 a2 = *(const half8*)(smem + (CB) * 8192 + 2 * 1024 + lane * 16);  \
        half8 a3 = *(const half8*)(smem + (CB) * 8192 + 3 * 1024 + lane * 16);  \
        __builtin_amdgcn_s_setprio(1);                                          \
        _Pragma("unroll") for (int mf = 0; mf < 4; ++mf) {                      \
            half8 am = (mf == 0) ? a0 : (mf == 1) ? a1 : (mf == 2) ? a2 : a3;   \
            acc[mf][0] = __builtin_amdgcn_mfma_f32_16x16x32_f16(am, bc0, acc[mf][0], 0, 0, 0); \
            acc[mf][1] = __builtin_amdgcn_mfma_f32_16x16x32_f16(am, bc1, acc[mf][1], 0, 0, 0); \
            acc[mf][2] = __builtin_amdgcn_mfma_f32_16x16x32_f16(am, bc2, acc[mf][2], 0, 0, 0); \
            acc[mf][3] = __builtin_amdgcn_mfma_f32_16x16x32_f16(am, bc3, acc[mf][3], 0, 0, 0); \
        }                                                                       \
        __builtin_amdgcn_s_setprio(0);                                          \
        half8 a4 = *(const half8*)(smem + (CB) * 8192 + 4 * 1024 + lane * 16);  \
        half8 a5 = *(const half8*)(smem + (CB) * 8192 + 5 * 1024 + lane * 16);  \
        half8 a6 = *(const half8*)(smem + (CB) * 8192 + 6 * 1024 + lane * 16);  \
        half8 a7 = *(const half8*)(smem + (CB) * 8192 + 7 * 1024 + lane * 16);  \
        __builtin_amdgcn_s_setprio(1);                                          \
        _Pragma("unroll") for (int mf = 0; mf < 4; ++mf) {                      \
            half8 am = (mf == 0) ? a4 : (mf == 1) ? a5 : (mf == 2) ? a6 : a7;   \
            acc[4 + mf][0] = __builtin_amdgcn_mfma_f32_16x16x32_f16(am, bc0, acc[4 + mf][0], 0, 0, 0); \
            acc[4 + mf][1] = __builtin_amdgcn_mfma_f32_16x16x32_f16(am, bc1, acc[4 + mf][1], 0, 0, 0); \
            acc[4 + mf][2] = __builtin_amdgcn_mfma_f32_16x16x32_f16(am, bc2, acc[4 + mf][2], 0, 0, 0); \
            acc[4 + mf][3] = __builtin_amdgcn_mfma_f32_16x16x32_f16(am, bc3, acc[4 + mf][3], 0, 0, 0); \
        }                                                                       \
        __builtin_amdgcn_s_setprio(0);                                          \
        if (pf1) {                                                              \
            asm volatile("s_waitcnt lgkmcnt(0)" ::: "memory");                  \
            __builtin_amdgcn_sched_barrier(0);                                  \
            __builtin_amdgcn_s_barrier();                                       \
            bc0 = bn0; bc1 = bn1; bc2 = bn2; bc3 = bn3;                         \
        }                                                                       \
    } while (0)

    // ---- prologue: stage A(0) into buf0, load B(0), prefetch A(1) ----
    A_LOAD(0);
    bc0 = *(const half8*)(bptr);
    bc1 = *(const half8*)(bptr + 512);
    bc2 = *(const half8*)(bptr + 1024);
    bc3 = *(const half8*)(bptr + 1536);
    A_CVT_WRITE(0);
    A_LOAD(1);
    asm volatile("s_waitcnt lgkmcnt(0)" ::: "memory");
    __builtin_amdgcn_sched_barrier(0);
    __builtin_amdgcn_s_barrier();

    for (int k2 = 0; k2 < 16; ++k2) {
        STEP(2 * k2,     0, 1);
        STEP(2 * k2 + 1, 1, 0);
    }

    // ---- epilogue: h = acc + b1; gelu; *W2; reduce 256 cols per row ----
    __syncthreads();
    float* red = (float*)smem;  // [128][68]
    const int hi = lane >> 4, lc = lane & 15;
    float b1v[4], w2v[4];
#pragma unroll
    for (int nf = 0; nf < 4; ++nf) {
        int c = nb * 256 + w * 64 + nf * 16 + lc;
        b1v[nf] = b1[c];
        w2v[nf] = W2[c];
    }
#pragma unroll
    for (int mf = 0; mf < 8; ++mf) {
#pragma unroll
        for (int i = 0; i < 4; ++i) {
            float s = 0.f;
#pragma unroll
            for (int nf = 0; nf < 4; ++nf) {
                float h = acc[mf][nf][i] + b1v[nf];
                s = fmaf(gelu_exact(h), w2v[nf], s);
            }
            red[(mf * 16 + hi * 4 + i) * 68 + w * 17 + lc] = s;
        }
    }
    __syncthreads();
    if (t < 128) {
        float s = 0.f;
#pragma unroll
        for (int ww = 0; ww < 4; ++ww)
#pragma unroll
            for (int c = 0; c < 16; ++c) s += red[t * 68 + ww * 17 + c];
        sparts[(size_t)nb * tot + m0 + t] = s;
    }
}

// ---- flag + provisional select from screen scores ----
__global__ void flag_select_kernel(const float* __restrict__ sparts, int tot,
                                   int* __restrict__ sel_buf,
                                   int* __restrict__ flag_list,
                                   int* __restrict__ counter, int N, int nseg_tot) {
    int seg = blockIdx.x * 256 + threadIdx.x;
    if (seg >= nseg_tot) return;
    int b = seg >> 5, s = seg & 31;
    size_t base = (size_t)b * N + s * SEG_LEN;
    float sc[SEG_LEN];
#pragma unroll
    for (int j = 0; j < SEG_LEN; ++j) sc[j] = sparts[base + j] + sparts[base + j + tot];
    unsigned mask = 0;
    float best9 = 0.f;
    for (int it = 0; it < QUOTA; ++it) {
        float best = 0.f; int bi = 0; bool found = false;
        for (int i = 0; i < SEG_LEN; ++i) if (!((mask >> i) & 1u)) {
            if (!found || sc[i] > best) { best = sc[i]; bi = i; found = true; }
        }
        mask |= 1u << bi;
        best9 = best;
    }
    float best10 = 0.f; bool f10 = false;
    for (int i = 0; i < SEG_LEN; ++i) if (!((mask >> i) & 1u)) {
        if (!f10 || sc[i] > best10) { best10 = sc[i]; f10 = true; }
    }
    if (best9 - best10 > GAP_THR) {
        int c = 0;
        for (int i = 0; i < SEG_LEN; ++i)
            if ((mask >> i) & 1u) sel_buf[(size_t)seg * QUOTA + (c++)] = i;
    } else {
        int p = atomicAdd(counter, 1);
        flag_list[p] = seg;
    }
}

// ---- exact recheck (fp16-split 3-pass, proven numerics) of flagged segments ----
__global__ __launch_bounds__(512, 2)
void recheck_kernel(const float* __restrict__ X, const _Float16* __restrict__ B32,
                    const float* __restrict__ b1, const float* __restrict__ W2,
                    const int* __restrict__ flag_list, const int* __restrict__ counter,
                    int* __restrict__ sel_buf, int N) {
    const int count = *counter;
    const int jb = blockIdx.x;
    if (jb * 3 >= count) return;
    __shared__ __align__(16) char smem[73728];
    const int t = threadIdx.x, w = t >> 6, lane = t & 63;

    const int r_ = t >> 3, kq8 = t & 7;
    int q = r_ / 18, rr = r_ % 18;
    if (r_ >= 54) { q = 2; rr = 0; }
    int li = jb * 3 + q; if (li >= count) li = count - 1;
    const int sg = flag_list[li];
    const float* aRow = X + ((size_t)(sg >> 5) * N + (sg & 31) * SEG_LEN + rr) * H_DIM + kq8 * 4;
    const int rg = r_ >> 5, aks = kq8 >> 2, ahi = (kq8 >> 1) & 1;
    const int aoff = (rg * 2 + aks) * 1024 + (ahi * 32 + (r_ & 31)) * 16 + (kq8 & 1) * 8;

    f32x16 acc1[2][2] = {};
    f32x16 acc2[2][2] = {};
    float4 av = *(const float4*)aRow;

    for (int kt = 0; kt < 32; ++kt) {
#pragma unroll
        for (int r8 = 0; r8 < 8; ++r8) {
            int idx = r8 * 512 + t;
            gload_lds16(B32 + (size_t)kt * 32768 + (size_t)idx * 8,
                        smem + 8192 + (size_t)idx * 16);
        }
        {
            float xs[4] = {av.x, av.y, av.z, av.w};
            half4 h0, h1;
#pragma unroll
            for (int j = 0; j < 4; ++j) {
                _Float16 a = (_Float16)xs[j];
                float r = xs[j] - (float)a;
                h0[j] = a;
                h1[j] = (_Float16)(r * 2048.0f);
            }
            *(half4*)(smem + aoff) = h0;
            *(half4*)(smem + 4096 + aoff) = h1;
        }
        int ktn = kt < 31 ? kt + 1 : 31;
        av = *(const float4*)(aRow + ktn * 32);
        asm volatile("s_waitcnt vmcnt(1) lgkmcnt(0)" ::: "memory");
        __builtin_amdgcn_sched_barrier(0);
        __builtin_amdgcn_s_barrier();

        half8 a0[4], a1[4], b0[4], b1f[4];
#pragma unroll
        for (int mf = 0; mf < 2; ++mf)
#pragma unroll
            for (int ks2 = 0; ks2 < 2; ++ks2) {
                a0[mf * 2 + ks2] = *(const half8*)(smem + (mf * 2 + ks2) * 1024 + lane * 16);
                a1[mf * 2 + ks2] = *(const half8*)(smem + 4096 + (mf * 2 + ks2) * 1024 + lane * 16);
            }
        const char* bb = smem + 8192 + (w >> 2) * 32768;
#pragma unroll
        for (int nfl = 0; nfl < 2; ++nfl)
#pragma unroll
            for (int ks2 = 0; ks2 < 2; ++ks2) {
                b0[nfl * 2 + ks2]  = *(const half8*)(bb + ks2 * 8192 + ((w & 3) * 2 + nfl) * 1024 + lane * 16);
                b1f[nfl * 2 + ks2] = *(const half8*)(bb + 16384 + ks2 * 8192 + ((w & 3) * 2 + nfl) * 1024 + lane * 16);
            }
        __builtin_amdgcn_s_setprio(1);
#pragma unroll
        for (int mf = 0; mf < 2; ++mf)
#pragma unroll
            for (int nfl = 0; nfl < 2; ++nfl)
#pragma unroll
                for (int ks2 = 0; ks2 < 2; ++ks2)
                    acc1[mf][nfl] = __builtin_amdgcn_mfma_f32_32x32x16_f16(
                        a0[mf * 2 + ks2], b0[nfl * 2 + ks2], acc1[mf][nfl], 0, 0, 0);
#pragma unroll
        for (int mf = 0; mf < 2; ++mf)
#pragma unroll
            for (int nfl = 0; nfl < 2; ++nfl)
#pragma unroll
                for (int ks2 = 0; ks2 < 2; ++ks2)
                    acc2[mf][nfl] = __builtin_amdgcn_mfma_f32_32x32x16_f16(
                        a0[mf * 2 + ks2], b1f[nfl * 2 + ks2], acc2[mf][nfl], 0, 0, 0);
#pragma unroll
        for (int mf = 0; mf < 2; ++mf)
#pragma unroll
            for (int nfl = 0; nfl < 2; ++nfl)
#pragma unroll
                for (int ks2 = 0; ks2 < 2; ++ks2)
                    acc2[mf][nfl] = __builtin_amdgcn_mfma_f32_32x32x16_f16(
                        a1[mf * 2 + ks2], b0[nfl * 2 + ks2], acc2[mf][nfl], 0, 0, 0);
        __builtin_amdgcn_s_setprio(0);
        __builtin_amdgcn_s_barrier();
    }

    __syncthreads();
    float* red = (float*)smem;                 // [8][64][33]
    float b1v[2], w2v[2];
#pragma unroll
    for (int nfl = 0; nfl < 2; ++nfl) {
        int c = (w >> 2) * 256 + ((w & 3) * 2 + nfl) * 32 + (lane & 31);
        b1v[nfl] = b1[c];
        w2v[nfl] = W2[c];
    }
#pragma unroll
    for (int mf = 0; mf < 2; ++mf)
#pragma unroll
        for (int i = 0; i < 16; ++i) {
            float s = 0.f;
#pragma unroll
            for (int nfl = 0; nfl < 2; ++nfl) {
                float h = acc1[mf][nfl][i] + acc2[mf][nfl][i] * (1.0f / 2048.0f) + b1v[nfl];
                s = fmaf(gelu_exact(h), w2v[nfl], s);
            }
            int row = mf * 32 + (i & 3) + 8 * (i >> 2) + 4 * (lane >> 5);
            red[(w * 64 + row) * 33 + (lane & 31)] = s;
        }
    __syncthreads();
    float* sx = (float*)(smem + 67584);        // [64]
    if (t < 64) {
        float s = 0.f;
        for (int ww = 0; ww < 8; ++ww)
#pragma unroll
            for (int lc = 0; lc < 32; ++lc) s += red[(ww * 64 + t) * 33 + lc];
        sx[t] = s;
    }
    __syncthreads();
    if (t < 3 && jb * 3 + t < count) {
        int sg2 = flag_list[jb * 3 + t];
        const float* sv = sx + t * SEG_LEN;
        unsigned mask = 0;
        for (int it = 0; it < QUOTA; ++it) {
            float best = 0.f; int bi = 0; bool found = false;
            for (int i = 0; i < SEG_LEN; ++i) if (!((mask >> i) & 1u)) {
                if (!found || sv[i] > best) { best = sv[i]; bi = i; found = true; }
            }
            mask |= 1u << bi;
        }
        int c = 0;
        for (int i = 0; i < SEG_LEN; ++i)
            if ((mask >> i) & 1u) sel_buf[(size_t)sg2 * QUOTA + (c++)] = i;
    }
}

// ---- final gather of selected rows ----
__global__ void gather_kernel(const float* __restrict__ X, const int* __restrict__ sel_buf,
                              float* __restrict__ out, int N) {
    const int seg = blockIdx.x, b = blockIdx.y, t = threadIdx.x;
    const int* sel = sel_buf + ((size_t)b * N_SEG + seg) * QUOTA;
    const float4* xb = (const float4*)X + ((size_t)b * N + seg * SEG_LEN) * (H_DIM / 4);
    float4* ob = (float4*)out + ((size_t)b * N_SEG * QUOTA + seg * QUOTA) * (H_DIM / 4);
#pragma unroll
    for (int j = 0; j < QUOTA; ++j) {
        int r = sel[j];
        ob[(size_t)j * (H_DIM / 4) + t] = xb[(size_t)r * (H_DIM / 4) + t];
    }
}

extern "C" void kernel_launch(void* const* d_in, const int* in_sizes, int n_in,
                              void* d_out, int out_size, void* d_ws, size_t ws_size,
                              hipStream_t stream) {
    const float* X  = (const float*)d_in[0];
    const float* W1 = (const float*)d_in[1];
    const float* b1 = (const float*)d_in[2];
    const float* W2 = (const float*)d_in[3];
    float* out = (float*)d_out;

    const int Hh = in_sizes[2];                        // 512
    const int H  = Hh * 2;                             // 1024
    const long long TOT = (long long)in_sizes[0] / H;  // 147456 tokens
    const int B = 256;
    const int N = (int)(TOT / B);                      // 576
    const int nseg_tot = B * N_SEG;                    // 8192

    char* ws = (char*)d_ws;
    _Float16* B32 = (_Float16*)(ws + 0);               // 2 MB
    _Float16* B16 = (_Float16*)(ws + 2097152);         // 1 MB
    float* sparts = (float*)(ws + 3145728);            // 2*TOT f32
    int* sel_buf  = (int*)(ws + 4325376);              // 8192*9
    int* flag_list= (int*)(ws + 4620288);              // 8192
    int* counter  = (int*)(ws + 4653056);

    hipMemsetAsync(counter, 0, 16, stream);

    hipLaunchKernelGGL(pack_w1_kernel, dim3(512), dim3(256), 0, stream, W1, B32, B16);

    hipLaunchKernelGGL(stage1_kernel, dim3((unsigned)(TOT / 128), 2), dim3(256), 0, stream,
                       X, B16, b1, W2, sparts, (int)TOT);

    hipLaunchKernelGGL(flag_select_kernel, dim3((nseg_tot + 255) / 256), dim3(256), 0, stream,
                       sparts, (int)TOT, sel_buf, flag_list, counter, N, nseg_tot);

    hipLaunchKernelGGL(recheck_kernel, dim3((nseg_tot + 2) / 3), dim3(512), 0, stream,
                       X, B32, b1, W2, flag_list, counter, sel_buf, N);

    hipLaunchKernelGGL(gather_kernel, dim3(N_SEG, B), dim3(256), 0, stream,
                       X, sel_buf, out, N);
}

// Round 14
// 572.685 us; speedup vs baseline: 1.7337x; 1.0713x over previous
//
#include <hip/hip_runtime.h>
#include <math.h>

#define H_DIM 1024
#define SEG_LEN 18
#define N_SEG 32
#define QUOTA 9
#define GAP_THR 8.0e-4f

typedef _Float16 half8 __attribute__((ext_vector_type(8)));
typedef _Float16 half4 __attribute__((ext_vector_type(4)));
typedef float f32x4 __attribute__((ext_vector_type(4)));
typedef float f32x16 __attribute__((ext_vector_type(16)));

__device__ __forceinline__ void gload_lds16(const void* g, void* l) {
    __builtin_amdgcn_global_load_lds((const __attribute__((address_space(1))) uint32_t*)g,
                                     (__attribute__((address_space(3))) uint32_t*)l,
                                     16, 0, 0);
}

__device__ __forceinline__ float gelu_exact(float h) {
    return 0.5f * h * (1.0f + erff(h * 0.70710678118654752f));
}

// ---- pack W1 [512][1024] fp32 into two layouts ----
// B32 (2 MB): 32x32x16-frag order, 2 exact-split fp16 planes (recheck kernel).
// B16 (1 MB): 16x16x32-frag order, plane-0 only (screen kernel):
//   half-off = (ks*32 + nf16)*512 + lane*8 + j   (each frag = 1 KB contiguous)
__global__ void pack_w1_kernel(const float* __restrict__ W1,
                               _Float16* __restrict__ B32,
                               _Float16* __restrict__ B16) {
    const int bid = blockIdx.x, t = threadIdx.x;
    if (bid < 256) {
        int tid = bid * 256 + t;
        int q = tid & 127, n = tid >> 7;
        int kt = q >> 2, ksub = (q >> 1) & 1, hi = q & 1;
        int nb = n >> 8, nf = (n >> 5) & 7, nlo = n & 31;
        const float* src = W1 + (size_t)n * H_DIM + q * 8;
        float4 v0 = *(const float4*)src, v1 = *(const float4*)(src + 4);
        float xs[8] = {v0.x, v0.y, v0.z, v0.w, v1.x, v1.y, v1.z, v1.w};
        half8 h0, h1;
#pragma unroll
        for (int j = 0; j < 8; ++j) {
            _Float16 a = (_Float16)xs[j];
            float r = xs[j] - (float)a;
            h0[j] = a;
            h1[j] = (_Float16)(r * 2048.0f);
        }
        size_t base = (size_t)kt * 32768 + nb * 16384 + ksub * 4096 + nf * 512
                    + (size_t)(hi * 32 + nlo) * 8;
        *(half8*)(B32 + base) = h0;
        *(half8*)(B32 + base + 8192) = h1;
    } else {
        int tid = (bid - 256) * 256 + t;
        int lane = tid & 63, nf = (tid >> 6) & 31, ks = tid >> 11;
        int n = nf * 16 + (lane & 15), k0 = ks * 32 + (lane >> 4) * 8;
        const float* src = W1 + (size_t)n * H_DIM + k0;
        float4 v0 = *(const float4*)src, v1 = *(const float4*)(src + 4);
        float xs[8] = {v0.x, v0.y, v0.z, v0.w, v1.x, v1.y, v1.z, v1.w};
        half8 h0;
#pragma unroll
        for (int j = 0; j < 8; ++j) h0[j] = (_Float16)xs[j];
        *(half8*)(B16 + ((size_t)(ks * 32 + nf)) * 512 + lane * 8) = h0;
    }
}

// ---- stage-1 scorer: R11 base + 4-step A-tiles (barrier per 4 K-steps) ----
// 64 rows x 256 cols (nb half), 4 waves of 64x64. A staged cooperatively in
// 16 KB tiles (4 sub-steps x 4 KB), double-buffered: ONE lgkm-only barrier
// per tile (8 total, was 32). B direct from L2 in fragment order with 2-deep
// bank rotation (no per-step vmcnt drain). Sub-steps are barrier-free.
__global__ __launch_bounds__(256, 3)
void stage1_kernel(const float* __restrict__ X, const _Float16* __restrict__ B16,
                   const float* __restrict__ b1, const float* __restrict__ W2,
                   float* __restrict__ sparts, int tot) {
    __shared__ __align__(16) char smem[32768];  // A dbuf 2x16KB; red[4][64][17] overlays
    const int t = threadIdx.x, w = t >> 6, lane = t & 63;
    const int nb = blockIdx.y;
    const size_t m0 = (size_t)blockIdx.x * 64;

    // A staging role (R11 mapping): wave w stages rows w*16..w*16+15;
    // lane->(row l&15, octet l>>4 within its 16-thread col group)
    const int arow = w * 16 + (t & 15);
    const int aq = (t >> 4) & 3;
    const float* aptr = X + (m0 + arow) * H_DIM + aq * 8;
    const int awoff = w * 1024 + ((t & 15) + 16 * aq) * 16;  // within 4KB sub-slab
    // B direct: frag (ks, nb*16 + w*4 + j) at bptr + ks*16384 + j*512 (halves)
    const _Float16* bptr = B16 + ((size_t)(nb * 16 + w * 4)) * 512 + lane * 8;

    f32x4 acc[4][4] = {};
    float4 av[4][2];          // pending raw A, one slot per sub-step
    half8 bk0[4], bk1[4];     // B banks: even-ks / odd-ks

#define AV_LOAD(s, ks)                                                          \
    do {                                                                        \
        av[s][0] = *(const float4*)(aptr + (ks) * 32);                          \
        av[s][1] = *(const float4*)(aptr + (ks) * 32 + 4);                      \
    } while (0)

#define AV_CVTW(s, base)                                                        \
    do {                                                                        \
        float4 u = av[s][0], v = av[s][1];                                      \
        half8 h_;                                                               \
        h_[0] = (_Float16)u.x; h_[1] = (_Float16)u.y;                           \
        h_[2] = (_Float16)u.z; h_[3] = (_Float16)u.w;                           \
        h_[4] = (_Float16)v.x; h_[5] = (_Float16)v.y;                           \
        h_[6] = (_Float16)v.z; h_[7] = (_Float16)v.w;                           \
        *(half8*)((base) + (s) * 4096 + awoff) = h_;                            \
    } while (0)

#define B_LOAD(BK, ks)                                                          \
    do {                                                                        \
        const _Float16* bp_ = bptr + (size_t)(ks) * 16384;                      \
        BK[0] = *(const half8*)(bp_);                                           \
        BK[1] = *(const half8*)(bp_ + 512);                                     \
        BK[2] = *(const half8*)(bp_ + 1024);                                    \
        BK[3] = *(const half8*)(bp_ + 1536);                                    \
    } while (0)

#define SUB(T, s, BK)                                                           \
    do {                                                                        \
        const int ks_ = 4 * (T) + (s);                                          \
        char* cb_ = smem + ((T) & 1) * 16384;                                   \
        char* nb_ = smem + (((T) + 1) & 1) * 16384;                             \
        if (ks_ < 28) AV_CVTW(s, nb_);      /* write tile T+1 sub s */          \
        if (ks_ < 24) AV_LOAD(s, ks_ + 8);  /* refill for tile T+2 */           \
        half8 a0 = *(const half8*)(cb_ + (s) * 4096 + 0 * 1024 + lane * 16);    \
        half8 a1 = *(const half8*)(cb_ + (s) * 4096 + 1 * 1024 + lane * 16);    \
        half8 a2 = *(const half8*)(cb_ + (s) * 4096 + 2 * 1024 + lane * 16);    \
        half8 a3 = *(const half8*)(cb_ + (s) * 4096 + 3 * 1024 + lane * 16);    \
        __builtin_amdgcn_s_setprio(1);                                          \
        acc[0][0] = __builtin_amdgcn_mfma_f32_16x16x32_f16(a0, BK[0], acc[0][0], 0, 0, 0); \
        acc[0][1] = __builtin_amdgcn_mfma_f32_16x16x32_f16(a0, BK[1], acc[0][1], 0, 0, 0); \
        acc[0][2] = __builtin_amdgcn_mfma_f32_16x16x32_f16(a0, BK[2], acc[0][2], 0, 0, 0); \
        acc[0][3] = __builtin_amdgcn_mfma_f32_16x16x32_f16(a0, BK[3], acc[0][3], 0, 0, 0); \
        acc[1][0] = __builtin_amdgcn_mfma_f32_16x16x32_f16(a1, BK[0], acc[1][0], 0, 0, 0); \
        acc[1][1] = __builtin_amdgcn_mfma_f32_16x16x32_f16(a1, BK[1], acc[1][1], 0, 0, 0); \
        acc[1][2] = __builtin_amdgcn_mfma_f32_16x16x32_f16(a1, BK[2], acc[1][2], 0, 0, 0); \
        acc[1][3] = __builtin_amdgcn_mfma_f32_16x16x32_f16(a1, BK[3], acc[1][3], 0, 0, 0); \
        acc[2][0] = __builtin_amdgcn_mfma_f32_16x16x32_f16(a2, BK[0], acc[2][0], 0, 0, 0); \
        acc[2][1] = __builtin_amdgcn_mfma_f32_16x16x32_f16(a2, BK[1], acc[2][1], 0, 0, 0); \
        acc[2][2] = __builtin_amdgcn_mfma_f32_16x16x32_f16(a2, BK[2], acc[2][2], 0, 0, 0); \
        acc[2][3] = __builtin_amdgcn_mfma_f32_16x16x32_f16(a2, BK[3], acc[2][3], 0, 0, 0); \
        acc[3][0] = __builtin_amdgcn_mfma_f32_16x16x32_f16(a3, BK[0], acc[3][0], 0, 0, 0); \
        acc[3][1] = __builtin_amdgcn_mfma_f32_16x16x32_f16(a3, BK[1], acc[3][1], 0, 0, 0); \
        acc[3][2] = __builtin_amdgcn_mfma_f32_16x16x32_f16(a3, BK[2], acc[3][2], 0, 0, 0); \
        acc[3][3] = __builtin_amdgcn_mfma_f32_16x16x32_f16(a3, BK[3], acc[3][3], 0, 0, 0); \
        __builtin_amdgcn_s_setprio(0);                                          \
        if (ks_ <= 29) B_LOAD(BK, ks_ + 2);  /* refill consumed bank, 2-deep */ \
        if ((s) == 3) {                                                         \
            asm volatile("s_waitcnt lgkmcnt(0)" ::: "memory");                  \
            __builtin_amdgcn_sched_barrier(0);                                  \
            __builtin_amdgcn_s_barrier();                                       \
        }                                                                       \
    } while (0)

    // ---- prologue: tile0 -> buf0; av <- tile1; B banks <- ks 0,1 ----
    AV_LOAD(0, 0); AV_LOAD(1, 1); AV_LOAD(2, 2); AV_LOAD(3, 3);
    B_LOAD(bk0, 0); B_LOAD(bk1, 1);
    AV_CVTW(0, smem); AV_CVTW(1, smem); AV_CVTW(2, smem); AV_CVTW(3, smem);
    AV_LOAD(0, 4); AV_LOAD(1, 5); AV_LOAD(2, 6); AV_LOAD(3, 7);
    asm volatile("s_waitcnt lgkmcnt(0)" ::: "memory");
    __builtin_amdgcn_sched_barrier(0);
    __builtin_amdgcn_s_barrier();

    for (int T = 0; T < 8; ++T) {
        SUB(T, 0, bk0);
        SUB(T, 1, bk1);
        SUB(T, 2, bk0);
        SUB(T, 3, bk1);
    }

    // ---- epilogue: h = acc + b1; gelu; *W2; reduce 256 cols -> partials ----
    __syncthreads();
    float* red = (float*)smem;  // [4][64][17]
    const int hi = lane >> 4, lc = lane & 15;
    float b1v[4], w2v[4];
#pragma unroll
    for (int nf = 0; nf < 4; ++nf) {
        int c = nb * 256 + w * 64 + nf * 16 + lc;
        b1v[nf] = b1[c];
        w2v[nf] = W2[c];
    }
#pragma unroll
    for (int mf = 0; mf < 4; ++mf) {
#pragma unroll
        for (int i = 0; i < 4; ++i) {
            float s = 0.f;
#pragma unroll
            for (int nf = 0; nf < 4; ++nf) {
                float h = acc[mf][nf][i] + b1v[nf];
                s = fmaf(gelu_exact(h), w2v[nf], s);
            }
            red[(w * 64 + mf * 16 + hi * 4 + i) * 17 + lc] = s;
        }
    }
    __syncthreads();
    if (t < 64) {
        float s = 0.f;
#pragma unroll
        for (int ww = 0; ww < 4; ++ww)
#pragma unroll
            for (int c = 0; c < 16; ++c) s += red[(ww * 64 + t) * 17 + c];
        sparts[(size_t)nb * tot + m0 + t] = s;
    }
}

// ---- flag + provisional select from screen scores ----
__global__ void flag_select_kernel(const float* __restrict__ sparts, int tot,
                                   int* __restrict__ sel_buf,
                                   int* __restrict__ flag_list,
                                   int* __restrict__ counter, int N, int nseg_tot) {
    int seg = blockIdx.x * 256 + threadIdx.x;
    if (seg >= nseg_tot) return;
    int b = seg >> 5, s = seg & 31;
    size_t base = (size_t)b * N + s * SEG_LEN;
    float sc[SEG_LEN];
#pragma unroll
    for (int j = 0; j < SEG_LEN; ++j) sc[j] = sparts[base + j] + sparts[base + j + tot];
    unsigned mask = 0;
    float best9 = 0.f;
    for (int it = 0; it < QUOTA; ++it) {
        float best = 0.f; int bi = 0; bool found = false;
        for (int i = 0; i < SEG_LEN; ++i) if (!((mask >> i) & 1u)) {
            if (!found || sc[i] > best) { best = sc[i]; bi = i; found = true; }
        }
        mask |= 1u << bi;
        best9 = best;
    }
    float best10 = 0.f; bool f10 = false;
    for (int i = 0; i < SEG_LEN; ++i) if (!((mask >> i) & 1u)) {
        if (!f10 || sc[i] > best10) { best10 = sc[i]; f10 = true; }
    }
    if (best9 - best10 > GAP_THR) {
        int c = 0;
        for (int i = 0; i < SEG_LEN; ++i)
            if ((mask >> i) & 1u) sel_buf[(size_t)seg * QUOTA + (c++)] = i;
    } else {
        int p = atomicAdd(counter, 1);
        flag_list[p] = seg;
    }
}

// ---- exact recheck (fp16-split 3-pass, proven numerics) of flagged segments ----
__global__ __launch_bounds__(512, 2)
void recheck_kernel(const float* __restrict__ X, const _Float16* __restrict__ B32,
                    const float* __restrict__ b1, const float* __restrict__ W2,
                    const int* __restrict__ flag_list, const int* __restrict__ counter,
                    int* __restrict__ sel_buf, int N) {
    const int count = *counter;
    const int jb = blockIdx.x;
    if (jb * 3 >= count) return;
    __shared__ __align__(16) char smem[73728];
    const int t = threadIdx.x, w = t >> 6, lane = t & 63;

    const int r_ = t >> 3, kq8 = t & 7;
    int q = r_ / 18, rr = r_ % 18;
    if (r_ >= 54) { q = 2; rr = 0; }
    int li = jb * 3 + q; if (li >= count) li = count - 1;
    const int sg = flag_list[li];
    const float* aRow = X + ((size_t)(sg >> 5) * N + (sg & 31) * SEG_LEN + rr) * H_DIM + kq8 * 4;
    const int rg = r_ >> 5, aks = kq8 >> 2, ahi = (kq8 >> 1) & 1;
    const int aoff = (rg * 2 + aks) * 1024 + (ahi * 32 + (r_ & 31)) * 16 + (kq8 & 1) * 8;

    f32x16 acc1[2][2] = {};
    f32x16 acc2[2][2] = {};
    float4 av = *(const float4*)aRow;

    for (int kt = 0; kt < 32; ++kt) {
#pragma unroll
        for (int r8 = 0; r8 < 8; ++r8) {
            int idx = r8 * 512 + t;
            gload_lds16(B32 + (size_t)kt * 32768 + (size_t)idx * 8,
                        smem + 8192 + (size_t)idx * 16);
        }
        {
            float xs[4] = {av.x, av.y, av.z, av.w};
            half4 h0, h1;
#pragma unroll
            for (int j = 0; j < 4; ++j) {
                _Float16 a = (_Float16)xs[j];
                float r = xs[j] - (float)a;
                h0[j] = a;
                h1[j] = (_Float16)(r * 2048.0f);
            }
            *(half4*)(smem + aoff) = h0;
            *(half4*)(smem + 4096 + aoff) = h1;
        }
        int ktn = kt < 31 ? kt + 1 : 31;
        av = *(const float4*)(aRow + ktn * 32);
        asm volatile("s_waitcnt vmcnt(1) lgkmcnt(0)" ::: "memory");
        __builtin_amdgcn_sched_barrier(0);
        __builtin_amdgcn_s_barrier();

        half8 a0[4], a1[4], b0[4], b1f[4];
#pragma unroll
        for (int mf = 0; mf < 2; ++mf)
#pragma unroll
            for (int ks2 = 0; ks2 < 2; ++ks2) {
                a0[mf * 2 + ks2] = *(const half8*)(smem + (mf * 2 + ks2) * 1024 + lane * 16);
                a1[mf * 2 + ks2] = *(const half8*)(smem + 4096 + (mf * 2 + ks2) * 1024 + lane * 16);
            }
        const char* bb = smem + 8192 + (w >> 2) * 32768;
#pragma unroll
        for (int nfl = 0; nfl < 2; ++nfl)
#pragma unroll
            for (int ks2 = 0; ks2 < 2; ++ks2) {
                b0[nfl * 2 + ks2]  = *(const half8*)(bb + ks2 * 8192 + ((w & 3) * 2 + nfl) * 1024 + lane * 16);
                b1f[nfl * 2 + ks2] = *(const half8*)(bb + 16384 + ks2 * 8192 + ((w & 3) * 2 + nfl) * 1024 + lane * 16);
            }
        __builtin_amdgcn_s_setprio(1);
#pragma unroll
        for (int mf = 0; mf < 2; ++mf)
#pragma unroll
            for (int nfl = 0; nfl < 2; ++nfl)
#pragma unroll
                for (int ks2 = 0; ks2 < 2; ++ks2)
                    acc1[mf][nfl] = __builtin_amdgcn_mfma_f32_32x32x16_f16(
                        a0[mf * 2 + ks2], b0[nfl * 2 + ks2], acc1[mf][nfl], 0, 0, 0);
#pragma unroll
        for (int mf = 0; mf < 2; ++mf)
#pragma unroll
            for (int nfl = 0; nfl < 2; ++nfl)
#pragma unroll
                for (int ks2 = 0; ks2 < 2; ++ks2)
                    acc2[mf][nfl] = __builtin_amdgcn_mfma_f32_32x32x16_f16(
                        a0[mf * 2 + ks2], b1f[nfl * 2 + ks2], acc2[mf][nfl], 0, 0, 0);
#pragma unroll
        for (int mf = 0; mf < 2; ++mf)
#pragma unroll
            for (int nfl = 0; nfl < 2; ++nfl)
#pragma unroll
                for (int ks2 = 0; ks2 < 2; ++ks2)
                    acc2[mf][nfl] = __builtin_amdgcn_mfma_f32_32x32x16_f16(
                        a1[mf * 2 + ks2], b0[nfl * 2 + ks2], acc2[mf][nfl], 0, 0, 0);
        __builtin_amdgcn_s_setprio(0);
        __builtin_amdgcn_s_barrier();
    }

    __syncthreads();
    float* red = (float*)smem;                 // [8][64][33]
    float b1v[2], w2v[2];
#pragma unroll
    for (int nfl = 0; nfl < 2; ++nfl) {
        int c = (w >> 2) * 256 + ((w & 3) * 2 + nfl) * 32 + (lane & 31);
        b1v[nfl] = b1[c];
        w2v[nfl] = W2[c];
    }
#pragma unroll
    for (int mf = 0; mf < 2; ++mf)
#pragma unroll
        for (int i = 0; i < 16; ++i) {
            float s = 0.f;
#pragma unroll
            for (int nfl = 0; nfl < 2; ++nfl) {
                float h = acc1[mf][nfl][i] + acc2[mf][nfl][i] * (1.0f / 2048.0f) + b1v[nfl];
                s = fmaf(gelu_exact(h), w2v[nfl], s);
            }
            int row = mf * 32 + (i & 3) + 8 * (i >> 2) + 4 * (lane >> 5);
            red[(w * 64 + row) * 33 + (lane & 31)] = s;
        }
    __syncthreads();
    float* sx = (float*)(smem + 67584);        // [64]
    if (t < 64) {
        float s = 0.f;
        for (int ww = 0; ww < 8; ++ww)
#pragma unroll
            for (int lc = 0; lc < 32; ++lc) s += red[(ww * 64 + t) * 33 + lc];
        sx[t] = s;
    }
    __syncthreads();
    if (t < 3 && jb * 3 + t < count) {
        int sg2 = flag_list[jb * 3 + t];
        const float* sv = sx + t * SEG_LEN;
        unsigned mask = 0;
        for (int it = 0; it < QUOTA; ++it) {
            float best = 0.f; int bi = 0; bool found = false;
            for (int i = 0; i < SEG_LEN; ++i) if (!((mask >> i) & 1u)) {
                if (!found || sv[i] > best) { best = sv[i]; bi = i; found = true; }
            }
            mask |= 1u << bi;
        }
        int c = 0;
        for (int i = 0; i < SEG_LEN; ++i)
            if ((mask >> i) & 1u) sel_buf[(size_t)sg2 * QUOTA + (c++)] = i;
    }
}

// ---- final gather of selected rows ----
__global__ void gather_kernel(const float* __restrict__ X, const int* __restrict__ sel_buf,
                              float* __restrict__ out, int N) {
    const int seg = blockIdx.x, b = blockIdx.y, t = threadIdx.x;
    const int* sel = sel_buf + ((size_t)b * N_SEG + seg) * QUOTA;
    const float4* xb = (const float4*)X + ((size_t)b * N + seg * SEG_LEN) * (H_DIM / 4);
    float4* ob = (float4*)out + ((size_t)b * N_SEG * QUOTA + seg * QUOTA) * (H_DIM / 4);
#pragma unroll
    for (int j = 0; j < QUOTA; ++j) {
        int r = sel[j];
        ob[(size_t)j * (H_DIM / 4) + t] = xb[(size_t)r * (H_DIM / 4) + t];
    }
}

extern "C" void kernel_launch(void* const* d_in, const int* in_sizes, int n_in,
                              void* d_out, int out_size, void* d_ws, size_t ws_size,
                              hipStream_t stream) {
    const float* X  = (const float*)d_in[0];
    const float* W1 = (const float*)d_in[1];
    const float* b1 = (const float*)d_in[2];
    const float* W2 = (const float*)d_in[3];
    float* out = (float*)d_out;

    const int Hh = in_sizes[2];                        // 512
    const int H  = Hh * 2;                             // 1024
    const long long TOT = (long long)in_sizes[0] / H;  // 147456 tokens
    const int B = 256;
    const int N = (int)(TOT / B);                      // 576
    const int nseg_tot = B * N_SEG;                    // 8192

    char* ws = (char*)d_ws;
    _Float16* B32 = (_Float16*)(ws + 0);               // 2 MB
    _Float16* B16 = (_Float16*)(ws + 2097152);         // 1 MB
    float* sparts = (float*)(ws + 3145728);            // 2*TOT f32
    int* sel_buf  = (int*)(ws + 4325376);              // 8192*9
    int* flag_list= (int*)(ws + 4620288);              // 8192
    int* counter  = (int*)(ws + 4653056);

    hipMemsetAsync(counter, 0, 16, stream);

    hipLaunchKernelGGL(pack_w1_kernel, dim3(512), dim3(256), 0, stream, W1, B32, B16);

    hipLaunchKernelGGL(stage1_kernel, dim3((unsigned)(TOT / 64), 2), dim3(256), 0, stream,
                       X, B16, b1, W2, sparts, (int)TOT);

    hipLaunchKernelGGL(flag_select_kernel, dim3((nseg_tot + 255) / 256), dim3(256), 0, stream,
                       sparts, (int)TOT, sel_buf, flag_list, counter, N, nseg_tot);

    hipLaunchKernelGGL(recheck_kernel, dim3((nseg_tot + 2) / 3), dim3(512), 0, stream,
                       X, B32, b1, W2, flag_list, counter, sel_buf, N);

    hipLaunchKernelGGL(gather_kernel, dim3(N_SEG, B), dim3(256), 0, stream,
                       X, sel_buf, out, N);
}